// Round 1
// baseline (1502.331 us; speedup 1.0000x reference)
//
#include <hip/hip_runtime.h>
#include <stdint.h>

#define N_NODES 50000
#define N_EDGES 800000
#define IN_DIM  128
#define HID_DIM 64
#define OUT_DIM 64

// ---------------------------------------------------------------------------
// k_init: dinv[i] = 1.0f (self-loop degree), a1[:] = 0
// ---------------------------------------------------------------------------
__global__ void k_init(float* __restrict__ dinv, float* __restrict__ a1, int n, int total) {
    int i = blockIdx.x * blockDim.x + threadIdx.x;
    int stride = gridDim.x * blockDim.x;
    for (; i < total; i += stride) {
        if (i < n) dinv[i] = 1.0f;
        a1[i] = 0.0f;
    }
}

// ---------------------------------------------------------------------------
// k_deg: dinv[dst] += 1 per edge (float atomics; dinv starts at 1.0)
// ---------------------------------------------------------------------------
__global__ void k_deg(const int* __restrict__ ei, float* __restrict__ dinv) {
    int e = blockIdx.x * blockDim.x + threadIdx.x;
    if (e < N_EDGES) {
        int d = ei[N_EDGES + e];   // edge_index[1][e]
        atomicAdd(&dinv[d], 1.0f);
    }
}

// ---------------------------------------------------------------------------
// k_rsqrt: dinv[i] = rsqrt(deg[i])
// ---------------------------------------------------------------------------
__global__ void k_rsqrt(float* __restrict__ dinv, int n) {
    int i = blockIdx.x * blockDim.x + threadIdx.x;
    if (i < n) dinv[i] = rsqrtf(dinv[i]);
}

// ---------------------------------------------------------------------------
// k_prep: unpack edges to int32 + precompute norm[e] = dinv[src]*dinv[dst]
// ---------------------------------------------------------------------------
__global__ void k_prep(const int* __restrict__ ei, const float* __restrict__ dinv,
                       int* __restrict__ src32, int* __restrict__ dst32,
                       float* __restrict__ norm) {
    int e = blockIdx.x * blockDim.x + threadIdx.x;
    if (e < N_EDGES) {
        int s = ei[e];
        int d = ei[N_EDGES + e];
        src32[e] = s;
        dst32[e] = d;
        norm[e] = dinv[s] * dinv[d];
    }
}

// ---------------------------------------------------------------------------
// k_gemm: H[n,64] = X[n,K] @ W[K,64].  Block = 256 threads = 4 rows x 64 cols.
// W staged fully in LDS (K*64*4B <= 32KB), X rows staged in LDS.
// ---------------------------------------------------------------------------
__global__ __launch_bounds__(256) void k_gemm(const float* __restrict__ X,
                                              const float* __restrict__ W,
                                              float* __restrict__ H, int n, int K) {
    __shared__ float Ws[IN_DIM * 64];   // max K = 128
    __shared__ float Xs[4][IN_DIM];
    const int c = threadIdx.x & 63;
    const int r = threadIdx.x >> 6;
    const int row0 = blockIdx.x * 4;

    for (int i = threadIdx.x; i < K * 64; i += 256) Ws[i] = W[i];
    for (int i = threadIdx.x; i < 4 * K; i += 256) {
        int rr = i / K, kk = i - rr * K;
        int row = row0 + rr;
        Xs[rr][kk] = (row < n) ? X[(size_t)row * K + kk] : 0.0f;
    }
    __syncthreads();

    if (row0 + r >= n) return;
    float acc = 0.0f;
#pragma unroll 8
    for (int k = 0; k < K; ++k) acc += Xs[r][k] * Ws[k * 64 + c];
    H[(size_t)(row0 + r) * 64 + c] = acc;
}

// ---------------------------------------------------------------------------
// k_agg: scatter-add messages.  16 lanes per edge, each lane handles 4 dims.
// OUT[dst, :] += H[src, :] * norm[e]
// ---------------------------------------------------------------------------
__global__ __launch_bounds__(256) void k_agg(const int* __restrict__ src32,
                                             const int* __restrict__ dst32,
                                             const float* __restrict__ norm,
                                             const float* __restrict__ H,
                                             float* __restrict__ OUT) {
    int t = blockIdx.x * blockDim.x + threadIdx.x;
    int e = t >> 4;
    int lane = t & 15;
    if (e >= N_EDGES) return;
    int s = src32[e];
    int d = dst32[e];
    float nm = norm[e];
    const float4 v = *reinterpret_cast<const float4*>(&H[(size_t)s * 64 + lane * 4]);
    float* o = &OUT[(size_t)d * 64 + lane * 4];
    atomicAdd(o + 0, v.x * nm);
    atomicAdd(o + 1, v.y * nm);
    atomicAdd(o + 2, v.z * nm);
    atomicAdd(o + 3, v.w * nm);
}

// ---------------------------------------------------------------------------
// k_post1: h1 = relu(a1 + h*dinv^2 + b1)   (self-loop term folded in), in place
// ---------------------------------------------------------------------------
__global__ void k_post1(float* __restrict__ a1, const float* __restrict__ h,
                        const float* __restrict__ dinv, const float* __restrict__ b1,
                        int total) {
    int i = blockIdx.x * blockDim.x + threadIdx.x;
    if (i >= total) return;
    int node = i >> 6;
    int d = i & 63;
    float di = dinv[node];
    float v = a1[i] + h[i] * di * di + b1[d];
    a1[i] = fmaxf(v, 0.0f);
}

// ---------------------------------------------------------------------------
// k_init_out: out = b2 + h2*dinv^2  (bias + self-loop; scatter adds the rest)
// ---------------------------------------------------------------------------
__global__ void k_init_out(float* __restrict__ out, const float* __restrict__ h2,
                           const float* __restrict__ dinv, const float* __restrict__ b2,
                           int total) {
    int i = blockIdx.x * blockDim.x + threadIdx.x;
    if (i >= total) return;
    int node = i >> 6;
    int d = i & 63;
    float di = dinv[node];
    out[i] = b2[d] + h2[i] * di * di;
}

extern "C" void kernel_launch(void* const* d_in, const int* in_sizes, int n_in,
                              void* d_out, int out_size, void* d_ws, size_t ws_size,
                              hipStream_t stream) {
    const float* x  = (const float*)d_in[0];
    const int*   ei = (const int*)d_in[1];    // [2, N_EDGES] int32 (JAX x64 disabled)
    const float* W1 = (const float*)d_in[2];
    const float* b1 = (const float*)d_in[3];
    const float* W2 = (const float*)d_in[4];
    const float* b2 = (const float*)d_in[5];
    float* out = (float*)d_out;

    // Workspace carve-up (all fp32/int32, 4-byte aligned):
    //   dinv[N] | src32[E] | dst32[E] | norm[E] | h[N*64] | a1[N*64]  ~= 35.4 MB
    float* dinv  = (float*)d_ws;
    int*   src32 = (int*)(dinv + N_NODES);
    int*   dst32 = src32 + N_EDGES;
    float* norm  = (float*)(dst32 + N_EDGES);
    float* h     = norm + N_EDGES;
    float* a1    = h + (size_t)N_NODES * 64;

    const int total = N_NODES * 64;   // 3.2M

    // 1. init dinv=1, a1=0
    k_init<<<2048, 256, 0, stream>>>(dinv, a1, N_NODES, total);
    // 2. degree count
    k_deg<<<(N_EDGES + 255) / 256, 256, 0, stream>>>(ei, dinv);
    // 3. dinv = rsqrt(deg)
    k_rsqrt<<<(N_NODES + 255) / 256, 256, 0, stream>>>(dinv, N_NODES);
    // 4. edge prep (int32 src/dst + norm)
    k_prep<<<(N_EDGES + 255) / 256, 256, 0, stream>>>(ei, dinv, src32, dst32, norm);
    // 5. h = x @ W1
    k_gemm<<<(N_NODES + 3) / 4, 256, 0, stream>>>(x, W1, h, N_NODES, IN_DIM);
    // 6. a1 += scatter(h * norm)
    k_agg<<<(N_EDGES * 16 + 255) / 256, 256, 0, stream>>>(src32, dst32, norm, h, a1);
    // 7. h1 = relu(a1 + selfloop + b1), in place in a1
    k_post1<<<(total + 255) / 256, 256, 0, stream>>>(a1, h, dinv, b1, total);
    // 8. h2 = h1 @ W2 (into h buffer)
    k_gemm<<<(N_NODES + 3) / 4, 256, 0, stream>>>(a1, W2, h, N_NODES, HID_DIM);
    // 9. out = b2 + selfloop
    k_init_out<<<(total + 255) / 256, 256, 0, stream>>>(out, h, dinv, b2, total);
    // 10. out += scatter(h2 * norm)
    k_agg<<<(N_EDGES * 16 + 255) / 256, 256, 0, stream>>>(src32, dst32, norm, h, out);
}

// Round 2
// 377.486 us; speedup vs baseline: 3.9798x; 3.9798x over previous
//
#include <hip/hip_runtime.h>
#include <stdint.h>

#define N_NODES 50000
#define N_EDGES 800000
#define IN_DIM  128
#define HID_DIM 64
#define OUT_DIM 64

// ---------------------------------------------------------------------------
// k_zero: deg[i] = 0
// ---------------------------------------------------------------------------
__global__ void k_zero(int* __restrict__ deg, int n) {
    int i = blockIdx.x * blockDim.x + threadIdx.x;
    if (i < n) deg[i] = 0;
}

// ---------------------------------------------------------------------------
// k_hist: deg[dst]++ per edge (int atomics)
// ---------------------------------------------------------------------------
__global__ void k_hist(const int* __restrict__ ei, int* __restrict__ deg) {
    int e = blockIdx.x * blockDim.x + threadIdx.x;
    if (e < N_EDGES) atomicAdd(&deg[ei[N_EDGES + e]], 1);
}

// ---------------------------------------------------------------------------
// k_dinv: dinv[i] = rsqrt(deg[i] + 1)   (+1 = self loop)
// ---------------------------------------------------------------------------
__global__ void k_dinv(const int* __restrict__ deg, float* __restrict__ dinv, int n) {
    int i = blockIdx.x * blockDim.x + threadIdx.x;
    if (i < n) dinv[i] = rsqrtf((float)deg[i] + 1.0f);
}

// ---------------------------------------------------------------------------
// k_scan: single-block exclusive prefix sum of deg -> rowstart[N+1], cur copy
// ---------------------------------------------------------------------------
__global__ __launch_bounds__(1024) void k_scan(const int* __restrict__ deg,
                                               int* __restrict__ rowstart,
                                               int* __restrict__ cur) {
    __shared__ int part[1024];
    const int T = 1024;
    const int CH = (N_NODES + T - 1) / T;   // 49
    int t = threadIdx.x;
    int base = t * CH;
    int s = 0;
    for (int i = 0; i < CH; ++i) {
        int idx = base + i;
        if (idx < N_NODES) s += deg[idx];
    }
    part[t] = s;
    __syncthreads();
    // Hillis-Steele inclusive scan over 1024 partials
    for (int off = 1; off < T; off <<= 1) {
        int v = (t >= off) ? part[t - off] : 0;
        __syncthreads();
        part[t] += v;
        __syncthreads();
    }
    int excl = (t == 0) ? 0 : part[t - 1];
    for (int i = 0; i < CH; ++i) {
        int idx = base + i;
        if (idx < N_NODES) {
            rowstart[idx] = excl;
            cur[idx] = excl;
            excl += deg[idx];
        }
    }
    if (t == T - 1) rowstart[N_NODES] = excl;
}

// ---------------------------------------------------------------------------
// k_fill: scatter edges into CSR slots; record = {src, norm} packed as int2
// ---------------------------------------------------------------------------
__global__ void k_fill(const int* __restrict__ ei, const float* __restrict__ dinv,
                       int* __restrict__ cur, int2* __restrict__ edata) {
    int e = blockIdx.x * blockDim.x + threadIdx.x;
    if (e >= N_EDGES) return;
    int s = ei[e];
    int d = ei[N_EDGES + e];
    float nm = dinv[s] * dinv[d];
    int pos = atomicAdd(&cur[d], 1);
    edata[pos] = make_int2(s, __float_as_int(nm));
}

// ---------------------------------------------------------------------------
// k_gemm: H[n,64] = X[n,K] @ W[K,64].  Block = 256 threads = 4 rows x 64 cols.
// ---------------------------------------------------------------------------
__global__ __launch_bounds__(256) void k_gemm(const float* __restrict__ X,
                                              const float* __restrict__ W,
                                              float* __restrict__ H, int n, int K) {
    __shared__ float Ws[IN_DIM * 64];
    __shared__ float Xs[4][IN_DIM];
    const int c = threadIdx.x & 63;
    const int r = threadIdx.x >> 6;
    const int row0 = blockIdx.x * 4;

    for (int i = threadIdx.x; i < K * 64; i += 256) Ws[i] = W[i];
    for (int i = threadIdx.x; i < 4 * K; i += 256) {
        int rr = i / K, kk = i - rr * K;
        int row = row0 + rr;
        Xs[rr][kk] = (row < n) ? X[(size_t)row * K + kk] : 0.0f;
    }
    __syncthreads();

    if (row0 + r >= n) return;
    float acc = 0.0f;
#pragma unroll 8
    for (int k = 0; k < K; ++k) acc += Xs[r][k] * Ws[k * 64 + c];
    H[(size_t)(row0 + r) * 64 + c] = acc;
}

// ---------------------------------------------------------------------------
// k_gather: per-node CSR aggregation, fused bias + self-loop (+ ReLU).
// 16 lanes per node, float4 per lane. OUT[n,:] = sum_{e in CSR[n]} h[src]*norm
//                                              + h[n]*dinv[n]^2 + b  (relu?)
// ---------------------------------------------------------------------------
template <bool RELU>
__global__ __launch_bounds__(256) void k_gather(const int* __restrict__ rowstart,
                                                const int2* __restrict__ edata,
                                                const float* __restrict__ h,
                                                const float* __restrict__ dinv,
                                                const float* __restrict__ bias,
                                                float* __restrict__ out) {
    int node = blockIdx.x * 16 + (threadIdx.x >> 4);
    int lane = threadIdx.x & 15;
    if (node >= N_NODES) return;

    int start = rowstart[node];
    int end   = rowstart[node + 1];

    float4 acc = make_float4(0.f, 0.f, 0.f, 0.f);
    for (int j = start; j < end; ++j) {
        int2 ed = edata[j];                       // broadcast across 16 lanes
        float nm = __int_as_float(ed.y);
        const float4 v = *reinterpret_cast<const float4*>(&h[(size_t)ed.x * 64 + lane * 4]);
        acc.x += v.x * nm;
        acc.y += v.y * nm;
        acc.z += v.z * nm;
        acc.w += v.w * nm;
    }
    // self loop + bias
    float di = dinv[node];
    float w = di * di;
    const float4 hv = *reinterpret_cast<const float4*>(&h[(size_t)node * 64 + lane * 4]);
    const float4 bv = *reinterpret_cast<const float4*>(&bias[lane * 4]);
    acc.x += hv.x * w + bv.x;
    acc.y += hv.y * w + bv.y;
    acc.z += hv.z * w + bv.z;
    acc.w += hv.w * w + bv.w;
    if (RELU) {
        acc.x = fmaxf(acc.x, 0.f);
        acc.y = fmaxf(acc.y, 0.f);
        acc.z = fmaxf(acc.z, 0.f);
        acc.w = fmaxf(acc.w, 0.f);
    }
    *reinterpret_cast<float4*>(&out[(size_t)node * 64 + lane * 4]) = acc;
}

extern "C" void kernel_launch(void* const* d_in, const int* in_sizes, int n_in,
                              void* d_out, int out_size, void* d_ws, size_t ws_size,
                              hipStream_t stream) {
    const float* x  = (const float*)d_in[0];
    const int*   ei = (const int*)d_in[1];    // [2, N_EDGES] int32
    const float* W1 = (const float*)d_in[2];
    const float* b1 = (const float*)d_in[3];
    const float* W2 = (const float*)d_in[4];
    const float* b2 = (const float*)d_in[5];
    float* out = (float*)d_out;

    // Workspace carve-up:
    //   deg[N] | rowstart[N+1] | cur[N] | dinv[N] | edata[E]*8B | h[N*64] | a1[N*64]
    //   ~= 0.2 + 0.2 + 0.2 + 0.2 + 6.4 + 12.8 + 12.8 MB = ~32.8 MB
    int*   deg      = (int*)d_ws;
    int*   rowstart = deg + N_NODES;
    int*   cur      = rowstart + (N_NODES + 1);
    float* dinv     = (float*)(cur + N_NODES);
    int2*  edata    = (int2*)(dinv + N_NODES);
    float* h        = (float*)(edata + N_EDGES);
    float* a1       = h + (size_t)N_NODES * 64;

    // --- CSR build ---
    k_zero<<<(N_NODES + 255) / 256, 256, 0, stream>>>(deg, N_NODES);
    k_hist<<<(N_EDGES + 255) / 256, 256, 0, stream>>>(ei, deg);
    k_dinv<<<(N_NODES + 255) / 256, 256, 0, stream>>>(deg, dinv, N_NODES);
    k_scan<<<1, 1024, 0, stream>>>(deg, rowstart, cur);
    k_fill<<<(N_EDGES + 255) / 256, 256, 0, stream>>>(ei, dinv, cur, edata);

    // --- layer 1 ---
    k_gemm<<<(N_NODES + 3) / 4, 256, 0, stream>>>(x, W1, h, N_NODES, IN_DIM);
    k_gather<true><<<(N_NODES + 15) / 16, 256, 0, stream>>>(rowstart, edata, h, dinv, b1, a1);

    // --- layer 2 ---
    k_gemm<<<(N_NODES + 3) / 4, 256, 0, stream>>>(a1, W2, h, N_NODES, HID_DIM);
    k_gather<false><<<(N_NODES + 15) / 16, 256, 0, stream>>>(rowstart, edata, h, dinv, b2, out);
}

// Round 3
// 264.906 us; speedup vs baseline: 5.6712x; 1.4250x over previous
//
#include <hip/hip_runtime.h>
#include <stdint.h>

#define N_NODES 50000
#define N_EDGES 800000
#define IN_DIM  128
#define HID_DIM 64
#define OUT_DIM 64

#define SCAN_BLOCKS ((N_NODES + 255) / 256)   // 196

// ---------------------------------------------------------------------------
// k_zero: deg[i] = 0
// ---------------------------------------------------------------------------
__global__ void k_zero(int* __restrict__ deg, int n) {
    int i = blockIdx.x * blockDim.x + threadIdx.x;
    if (i < n) deg[i] = 0;
}

// ---------------------------------------------------------------------------
// k_hist: deg[dst]++ per edge (int atomics)
// ---------------------------------------------------------------------------
__global__ void k_hist(const int* __restrict__ ei, int* __restrict__ deg) {
    int e = blockIdx.x * blockDim.x + threadIdx.x;
    if (e < N_EDGES) atomicAdd(&deg[ei[N_EDGES + e]], 1);
}

// ---------------------------------------------------------------------------
// k_dinv: dinv[i] = rsqrt(deg[i] + 1)   (+1 = self loop)
// ---------------------------------------------------------------------------
__global__ void k_dinv(const int* __restrict__ deg, float* __restrict__ dinv, int n) {
    int i = blockIdx.x * blockDim.x + threadIdx.x;
    if (i < n) dinv[i] = rsqrtf((float)deg[i] + 1.0f);
}

// ---------------------------------------------------------------------------
// k_bsum: bsum[b] = sum of deg over block b's 256 nodes (wave shuffle reduce)
// ---------------------------------------------------------------------------
__global__ __launch_bounds__(256) void k_bsum(const int* __restrict__ deg,
                                              int* __restrict__ bsum) {
    int b = blockIdx.x, t = threadIdx.x;
    int node = b * 256 + t;
    int d = (node < N_NODES) ? deg[node] : 0;
    for (int o = 32; o > 0; o >>= 1) d += __shfl_down(d, o, 64);
    __shared__ int ws[4];
    int wid = t >> 6, lane = t & 63;
    if (lane == 0) ws[wid] = d;
    __syncthreads();
    if (t == 0) bsum[b] = ws[0] + ws[1] + ws[2] + ws[3];
}

// ---------------------------------------------------------------------------
// k_scan2: per-block exclusive scan. Block offset = sum(bsum[0..b-1]) computed
// in-block; local wave-shuffle scan of 256 degs; write rowstart & cur.
// ---------------------------------------------------------------------------
__global__ __launch_bounds__(256) void k_scan2(const int* __restrict__ deg,
                                               const int* __restrict__ bsum,
                                               int* __restrict__ rowstart,
                                               int* __restrict__ cur) {
    int b = blockIdx.x, t = threadIdx.x;
    int node = b * 256 + t;
    int wid = t >> 6, lane = t & 63;

    // ---- block offset: sum of preceding block sums ----
    int partial = 0;
    for (int i = t; i < b; i += 256) partial += bsum[i];
    for (int o = 32; o > 0; o >>= 1) partial += __shfl_down(partial, o, 64);
    __shared__ int ws[4];
    __shared__ int sh_off;
    if (lane == 0) ws[wid] = partial;
    __syncthreads();
    if (t == 0) sh_off = ws[0] + ws[1] + ws[2] + ws[3];
    __syncthreads();
    int off = sh_off;

    // ---- local inclusive scan (wave shuffle + cross-wave LDS) ----
    int d = (node < N_NODES) ? deg[node] : 0;
    int incl = d;
    for (int o = 1; o < 64; o <<= 1) {
        int v = __shfl_up(incl, o, 64);
        if (lane >= o) incl += v;
    }
    __shared__ int wtot[4];
    if (lane == 63) wtot[wid] = incl;
    __syncthreads();
    int woff = 0;
    for (int w = 0; w < wid; ++w) woff += wtot[w];

    int excl = off + woff + incl - d;
    if (node < N_NODES) {
        rowstart[node] = excl;
        cur[node] = excl;
        if (node == N_NODES - 1) rowstart[N_NODES] = excl + d;
    }
}

// ---------------------------------------------------------------------------
// k_fill: scatter edges into CSR slots; record = {src, norm} packed as int2
// ---------------------------------------------------------------------------
__global__ void k_fill(const int* __restrict__ ei, const float* __restrict__ dinv,
                       int* __restrict__ cur, int2* __restrict__ edata) {
    int e = blockIdx.x * blockDim.x + threadIdx.x;
    if (e >= N_EDGES) return;
    int s = ei[e];
    int d = ei[N_EDGES + e];
    float nm = dinv[s] * dinv[d];
    int pos = atomicAdd(&cur[d], 1);
    edata[pos] = make_int2(s, __float_as_int(nm));
}

// ---------------------------------------------------------------------------
// k_gemm: H[n,64] = X[n,K] @ W[K,64].  Block = 256 threads = 4 rows x 64 cols.
// ---------------------------------------------------------------------------
__global__ __launch_bounds__(256) void k_gemm(const float* __restrict__ X,
                                              const float* __restrict__ W,
                                              float* __restrict__ H, int n, int K) {
    __shared__ float Ws[IN_DIM * 64];
    __shared__ float Xs[4][IN_DIM];
    const int c = threadIdx.x & 63;
    const int r = threadIdx.x >> 6;
    const int row0 = blockIdx.x * 4;

    for (int i = threadIdx.x; i < K * 64; i += 256) Ws[i] = W[i];
    for (int i = threadIdx.x; i < 4 * K; i += 256) {
        int rr = i / K, kk = i - rr * K;
        int row = row0 + rr;
        Xs[rr][kk] = (row < n) ? X[(size_t)row * K + kk] : 0.0f;
    }
    __syncthreads();

    if (row0 + r >= n) return;
    float acc = 0.0f;
#pragma unroll 8
    for (int k = 0; k < K; ++k) acc += Xs[r][k] * Ws[k * 64 + c];
    H[(size_t)(row0 + r) * 64 + c] = acc;
}

// ---------------------------------------------------------------------------
// k_gather: per-node CSR aggregation, fused bias + self-loop (+ ReLU).
// ---------------------------------------------------------------------------
template <bool RELU>
__global__ __launch_bounds__(256) void k_gather(const int* __restrict__ rowstart,
                                                const int2* __restrict__ edata,
                                                const float* __restrict__ h,
                                                const float* __restrict__ dinv,
                                                const float* __restrict__ bias,
                                                float* __restrict__ out) {
    int node = blockIdx.x * 16 + (threadIdx.x >> 4);
    int lane = threadIdx.x & 15;
    if (node >= N_NODES) return;

    int start = rowstart[node];
    int end   = rowstart[node + 1];

    float4 acc = make_float4(0.f, 0.f, 0.f, 0.f);
    for (int j = start; j < end; ++j) {
        int2 ed = edata[j];                       // broadcast across 16 lanes
        float nm = __int_as_float(ed.y);
        const float4 v = *reinterpret_cast<const float4*>(&h[(size_t)ed.x * 64 + lane * 4]);
        acc.x += v.x * nm;
        acc.y += v.y * nm;
        acc.z += v.z * nm;
        acc.w += v.w * nm;
    }
    // self loop + bias
    float di = dinv[node];
    float w = di * di;
    const float4 hv = *reinterpret_cast<const float4*>(&h[(size_t)node * 64 + lane * 4]);
    const float4 bv = *reinterpret_cast<const float4*>(&bias[lane * 4]);
    acc.x += hv.x * w + bv.x;
    acc.y += hv.y * w + bv.y;
    acc.z += hv.z * w + bv.z;
    acc.w += hv.w * w + bv.w;
    if (RELU) {
        acc.x = fmaxf(acc.x, 0.f);
        acc.y = fmaxf(acc.y, 0.f);
        acc.z = fmaxf(acc.z, 0.f);
        acc.w = fmaxf(acc.w, 0.f);
    }
    *reinterpret_cast<float4*>(&out[(size_t)node * 64 + lane * 4]) = acc;
}

extern "C" void kernel_launch(void* const* d_in, const int* in_sizes, int n_in,
                              void* d_out, int out_size, void* d_ws, size_t ws_size,
                              hipStream_t stream) {
    const float* x  = (const float*)d_in[0];
    const int*   ei = (const int*)d_in[1];    // [2, N_EDGES] int32
    const float* W1 = (const float*)d_in[2];
    const float* b1 = (const float*)d_in[3];
    const float* W2 = (const float*)d_in[4];
    const float* b2 = (const float*)d_in[5];
    float* out = (float*)d_out;

    // Workspace carve-up:
    //   deg[N] | rowstart[N+1] | cur[N] | dinv[N] | bsum[196] | edata[E]*8B |
    //   h[N*64] | a1[N*64]   ~= 33 MB
    int*   deg      = (int*)d_ws;
    int*   rowstart = deg + N_NODES;
    int*   cur      = rowstart + (N_NODES + 1);
    float* dinv     = (float*)(cur + N_NODES);
    int*   bsum     = (int*)(dinv + N_NODES);
    int2*  edata    = (int2*)(bsum + ((SCAN_BLOCKS + 1) & ~1));
    float* h        = (float*)(edata + N_EDGES);
    float* a1       = h + (size_t)N_NODES * 64;

    // --- CSR build ---
    k_zero<<<(N_NODES + 255) / 256, 256, 0, stream>>>(deg, N_NODES);
    k_hist<<<(N_EDGES + 255) / 256, 256, 0, stream>>>(ei, deg);
    k_dinv<<<(N_NODES + 255) / 256, 256, 0, stream>>>(deg, dinv, N_NODES);
    k_bsum<<<SCAN_BLOCKS, 256, 0, stream>>>(deg, bsum);
    k_scan2<<<SCAN_BLOCKS, 256, 0, stream>>>(deg, bsum, rowstart, cur);
    k_fill<<<(N_EDGES + 255) / 256, 256, 0, stream>>>(ei, dinv, cur, edata);

    // --- layer 1 ---
    k_gemm<<<(N_NODES + 3) / 4, 256, 0, stream>>>(x, W1, h, N_NODES, IN_DIM);
    k_gather<true><<<(N_NODES + 15) / 16, 256, 0, stream>>>(rowstart, edata, h, dinv, b1, a1);

    // --- layer 2 ---
    k_gemm<<<(N_NODES + 3) / 4, 256, 0, stream>>>(a1, W2, h, N_NODES, HID_DIM);
    k_gather<false><<<(N_NODES + 15) / 16, 256, 0, stream>>>(rowstart, edata, h, dinv, b2, out);
}

// Round 4
// 244.962 us; speedup vs baseline: 6.1329x; 1.0814x over previous
//
#include <hip/hip_runtime.h>
#include <stdint.h>

#define N_NODES 50000
#define N_EDGES 800000
#define IN_DIM  128
#define HID_DIM 64
#define OUT_DIM 64

#define SCAN_BLOCKS ((N_NODES + 255) / 256)   // 196

// ---------------------------------------------------------------------------
// k_zero: deg[i] = 0
// ---------------------------------------------------------------------------
__global__ void k_zero(int* __restrict__ deg, int n) {
    int i = blockIdx.x * blockDim.x + threadIdx.x;
    if (i < n) deg[i] = 0;
}

// ---------------------------------------------------------------------------
// k_hist: deg[dst]++ per edge (int atomics)
// ---------------------------------------------------------------------------
__global__ void k_hist(const int* __restrict__ ei, int* __restrict__ deg) {
    int e = blockIdx.x * blockDim.x + threadIdx.x;
    if (e < N_EDGES) atomicAdd(&deg[ei[N_EDGES + e]], 1);
}

// ---------------------------------------------------------------------------
// k_dinv: dinv[i] = rsqrt(deg[i] + 1)   (+1 = self loop)
// ---------------------------------------------------------------------------
__global__ void k_dinv(const int* __restrict__ deg, float* __restrict__ dinv, int n) {
    int i = blockIdx.x * blockDim.x + threadIdx.x;
    if (i < n) dinv[i] = rsqrtf((float)deg[i] + 1.0f);
}

// ---------------------------------------------------------------------------
// k_bsum: bsum[b] = sum of deg over block b's 256 nodes (wave shuffle reduce)
// ---------------------------------------------------------------------------
__global__ __launch_bounds__(256) void k_bsum(const int* __restrict__ deg,
                                              int* __restrict__ bsum) {
    int b = blockIdx.x, t = threadIdx.x;
    int node = b * 256 + t;
    int d = (node < N_NODES) ? deg[node] : 0;
    for (int o = 32; o > 0; o >>= 1) d += __shfl_down(d, o, 64);
    __shared__ int ws[4];
    int wid = t >> 6, lane = t & 63;
    if (lane == 0) ws[wid] = d;
    __syncthreads();
    if (t == 0) bsum[b] = ws[0] + ws[1] + ws[2] + ws[3];
}

// ---------------------------------------------------------------------------
// k_scan2: per-block exclusive scan. Block offset = sum(bsum[0..b-1]) computed
// in-block; local wave-shuffle scan of 256 degs; write rowstart & cur.
// ---------------------------------------------------------------------------
__global__ __launch_bounds__(256) void k_scan2(const int* __restrict__ deg,
                                               const int* __restrict__ bsum,
                                               int* __restrict__ rowstart,
                                               int* __restrict__ cur) {
    int b = blockIdx.x, t = threadIdx.x;
    int node = b * 256 + t;
    int wid = t >> 6, lane = t & 63;

    // ---- block offset: sum of preceding block sums ----
    int partial = 0;
    for (int i = t; i < b; i += 256) partial += bsum[i];
    for (int o = 32; o > 0; o >>= 1) partial += __shfl_down(partial, o, 64);
    __shared__ int ws[4];
    __shared__ int sh_off;
    if (lane == 0) ws[wid] = partial;
    __syncthreads();
    if (t == 0) sh_off = ws[0] + ws[1] + ws[2] + ws[3];
    __syncthreads();
    int off = sh_off;

    // ---- local inclusive scan (wave shuffle + cross-wave LDS) ----
    int d = (node < N_NODES) ? deg[node] : 0;
    int incl = d;
    for (int o = 1; o < 64; o <<= 1) {
        int v = __shfl_up(incl, o, 64);
        if (lane >= o) incl += v;
    }
    __shared__ int wtot[4];
    if (lane == 63) wtot[wid] = incl;
    __syncthreads();
    int woff = 0;
    for (int w = 0; w < wid; ++w) woff += wtot[w];

    int excl = off + woff + incl - d;
    if (node < N_NODES) {
        rowstart[node] = excl;
        cur[node] = excl;
        if (node == N_NODES - 1) rowstart[N_NODES] = excl + d;
    }
}

// ---------------------------------------------------------------------------
// k_fill: scatter edges into CSR slots; record = {src, norm} packed as int2
// ---------------------------------------------------------------------------
__global__ void k_fill(const int* __restrict__ ei, const float* __restrict__ dinv,
                       int* __restrict__ cur, int2* __restrict__ edata) {
    int e = blockIdx.x * blockDim.x + threadIdx.x;
    if (e >= N_EDGES) return;
    int s = ei[e];
    int d = ei[N_EDGES + e];
    float nm = dinv[s] * dinv[d];
    int pos = atomicAdd(&cur[d], 1);
    edata[pos] = make_int2(s, __float_as_int(nm));
}

// ---------------------------------------------------------------------------
// k_gemm2: H[n,64] = X[n,K] @ W[K,64].  64 rows x 64 cols per block,
// 256 threads as 16x16, each thread a 4x4 register tile.
// W in LDS as [K][64] (float4 col reads); X in LDS [64][K] with XOR quad
// swizzle (q ^= r&7) for bank-conflict-free reads. LDS = 64KB (K=128).
// ---------------------------------------------------------------------------
template <int K>
__global__ __launch_bounds__(256) void k_gemm2(const float* __restrict__ X,
                                               const float* __restrict__ W,
                                               float* __restrict__ H, int n) {
    constexpr int QK = K / 4;                 // float4 quads per X row
    __shared__ float4 Ws[K * 16];             // [K][64] as quads
    __shared__ float4 Xs[64 * QK];            // [64][K] as swizzled quads
    const int tid = threadIdx.x;
    const int row0 = blockIdx.x * 64;

    // stage W (K*16 quads, coalesced)
#pragma unroll
    for (int f = tid; f < K * 16; f += 256) Ws[f] = ((const float4*)W)[f];
    // stage X rows row0..row0+63, swizzled quad column
#pragma unroll
    for (int f = tid; f < 64 * QK; f += 256) {
        int r = f / QK;
        int q = f - r * QK;
        int row = row0 + r;
        float4 v = (row < n) ? ((const float4*)X)[(size_t)row * QK + q]
                             : make_float4(0.f, 0.f, 0.f, 0.f);
        Xs[r * QK + (q ^ (r & 7))] = v;
    }
    __syncthreads();

    const int c4 = tid & 15;                  // col quad (cols c4*4..c4*4+3)
    const int rb = (tid >> 4) * 4;            // first of 4 rows

    float4 acc0 = make_float4(0.f, 0.f, 0.f, 0.f);
    float4 acc1 = make_float4(0.f, 0.f, 0.f, 0.f);
    float4 acc2 = make_float4(0.f, 0.f, 0.f, 0.f);
    float4 acc3 = make_float4(0.f, 0.f, 0.f, 0.f);

#pragma unroll 8
    for (int k = 0; k < K; k += 4) {
        const float4 w0 = Ws[(k + 0) * 16 + c4];
        const float4 w1 = Ws[(k + 1) * 16 + c4];
        const float4 w2 = Ws[(k + 2) * 16 + c4];
        const float4 w3 = Ws[(k + 3) * 16 + c4];
        const int k4 = k >> 2;
#pragma unroll
        for (int i = 0; i < 4; ++i) {
            const int r = rb + i;
            const float4 xv = Xs[r * QK + (k4 ^ (r & 7))];
            float4* acc = (i == 0) ? &acc0 : (i == 1) ? &acc1 : (i == 2) ? &acc2 : &acc3;
            acc->x += xv.x * w0.x + xv.y * w1.x + xv.z * w2.x + xv.w * w3.x;
            acc->y += xv.x * w0.y + xv.y * w1.y + xv.z * w2.y + xv.w * w3.y;
            acc->z += xv.x * w0.z + xv.y * w1.z + xv.z * w2.z + xv.w * w3.z;
            acc->w += xv.x * w0.w + xv.y * w1.w + xv.z * w2.w + xv.w * w3.w;
        }
    }

    const float4 accs[4] = {acc0, acc1, acc2, acc3};
#pragma unroll
    for (int i = 0; i < 4; ++i) {
        int row = row0 + rb + i;
        if (row < n) ((float4*)H)[(size_t)row * 16 + c4] = accs[i];
    }
}

// ---------------------------------------------------------------------------
// k_gather: per-node CSR aggregation, fused bias + self-loop (+ ReLU).
// ---------------------------------------------------------------------------
template <bool RELU>
__global__ __launch_bounds__(256) void k_gather(const int* __restrict__ rowstart,
                                                const int2* __restrict__ edata,
                                                const float* __restrict__ h,
                                                const float* __restrict__ dinv,
                                                const float* __restrict__ bias,
                                                float* __restrict__ out) {
    int node = blockIdx.x * 16 + (threadIdx.x >> 4);
    int lane = threadIdx.x & 15;
    if (node >= N_NODES) return;

    int start = rowstart[node];
    int end   = rowstart[node + 1];

    float4 acc = make_float4(0.f, 0.f, 0.f, 0.f);
    for (int j = start; j < end; ++j) {
        int2 ed = edata[j];                       // broadcast across 16 lanes
        float nm = __int_as_float(ed.y);
        const float4 v = *reinterpret_cast<const float4*>(&h[(size_t)ed.x * 64 + lane * 4]);
        acc.x += v.x * nm;
        acc.y += v.y * nm;
        acc.z += v.z * nm;
        acc.w += v.w * nm;
    }
    // self loop + bias
    float di = dinv[node];
    float w = di * di;
    const float4 hv = *reinterpret_cast<const float4*>(&h[(size_t)node * 64 + lane * 4]);
    const float4 bv = *reinterpret_cast<const float4*>(&bias[lane * 4]);
    acc.x += hv.x * w + bv.x;
    acc.y += hv.y * w + bv.y;
    acc.z += hv.z * w + bv.z;
    acc.w += hv.w * w + bv.w;
    if (RELU) {
        acc.x = fmaxf(acc.x, 0.f);
        acc.y = fmaxf(acc.y, 0.f);
        acc.z = fmaxf(acc.z, 0.f);
        acc.w = fmaxf(acc.w, 0.f);
    }
    *reinterpret_cast<float4*>(&out[(size_t)node * 64 + lane * 4]) = acc;
}

extern "C" void kernel_launch(void* const* d_in, const int* in_sizes, int n_in,
                              void* d_out, int out_size, void* d_ws, size_t ws_size,
                              hipStream_t stream) {
    const float* x  = (const float*)d_in[0];
    const int*   ei = (const int*)d_in[1];    // [2, N_EDGES] int32
    const float* W1 = (const float*)d_in[2];
    const float* b1 = (const float*)d_in[3];
    const float* W2 = (const float*)d_in[4];
    const float* b2 = (const float*)d_in[5];
    float* out = (float*)d_out;

    // Workspace carve-up:
    //   deg[N] | rowstart[N+1] | cur[N] | dinv[N] | bsum[196] | edata[E]*8B |
    //   h[N*64] | a1[N*64]   ~= 33 MB
    int*   deg      = (int*)d_ws;
    int*   rowstart = deg + N_NODES;
    int*   cur      = rowstart + (N_NODES + 1);
    float* dinv     = (float*)(cur + N_NODES);
    int*   bsum     = (int*)(dinv + N_NODES);
    int2*  edata    = (int2*)(bsum + ((SCAN_BLOCKS + 1) & ~1));
    float* h        = (float*)(edata + N_EDGES);
    float* a1       = h + (size_t)N_NODES * 64;

    // --- CSR build ---
    k_zero<<<(N_NODES + 255) / 256, 256, 0, stream>>>(deg, N_NODES);
    k_hist<<<(N_EDGES + 255) / 256, 256, 0, stream>>>(ei, deg);
    k_dinv<<<(N_NODES + 255) / 256, 256, 0, stream>>>(deg, dinv, N_NODES);
    k_bsum<<<SCAN_BLOCKS, 256, 0, stream>>>(deg, bsum);
    k_scan2<<<SCAN_BLOCKS, 256, 0, stream>>>(deg, bsum, rowstart, cur);
    k_fill<<<(N_EDGES + 255) / 256, 256, 0, stream>>>(ei, dinv, cur, edata);

    // --- layer 1 ---
    k_gemm2<IN_DIM><<<(N_NODES + 63) / 64, 256, 0, stream>>>(x, W1, h, N_NODES);
    k_gather<true><<<(N_NODES + 15) / 16, 256, 0, stream>>>(rowstart, edata, h, dinv, b1, a1);

    // --- layer 2 ---
    k_gemm2<HID_DIM><<<(N_NODES + 63) / 64, 256, 0, stream>>>(a1, W2, h, N_NODES);
    k_gather<false><<<(N_NODES + 15) / 16, 256, 0, stream>>>(rowstart, edata, h, dinv, b2, out);
}

// Round 5
// 220.404 us; speedup vs baseline: 6.8163x; 1.1114x over previous
//
#include <hip/hip_runtime.h>
#include <stdint.h>

#define N_NODES 50000
#define N_EDGES 800000
#define IN_DIM  128
#define HID_DIM 64
#define OUT_DIM 64

#define SCAN_BLOCKS ((N_NODES + 255) / 256)   // 196

// ---------------------------------------------------------------------------
// k_zero: deg[i] = 0
// ---------------------------------------------------------------------------
__global__ void k_zero(int* __restrict__ deg, int n) {
    int i = blockIdx.x * blockDim.x + threadIdx.x;
    if (i < n) deg[i] = 0;
}

// ---------------------------------------------------------------------------
// k_hist: deg[dst]++ per edge (int atomics)
// ---------------------------------------------------------------------------
__global__ void k_hist(const int* __restrict__ ei, int* __restrict__ deg) {
    int e = blockIdx.x * blockDim.x + threadIdx.x;
    if (e < N_EDGES) atomicAdd(&deg[ei[N_EDGES + e]], 1);
}

// ---------------------------------------------------------------------------
// k_dinv: dinv[i] = rsqrt(deg[i] + 1)   (+1 = self loop)
// ---------------------------------------------------------------------------
__global__ void k_dinv(const int* __restrict__ deg, float* __restrict__ dinv, int n) {
    int i = blockIdx.x * blockDim.x + threadIdx.x;
    if (i < n) dinv[i] = rsqrtf((float)deg[i] + 1.0f);
}

// ---------------------------------------------------------------------------
// k_bsum: bsum[b] = sum of deg over block b's 256 nodes (wave shuffle reduce)
// ---------------------------------------------------------------------------
__global__ __launch_bounds__(256) void k_bsum(const int* __restrict__ deg,
                                              int* __restrict__ bsum) {
    int b = blockIdx.x, t = threadIdx.x;
    int node = b * 256 + t;
    int d = (node < N_NODES) ? deg[node] : 0;
    for (int o = 32; o > 0; o >>= 1) d += __shfl_down(d, o, 64);
    __shared__ int ws[4];
    int wid = t >> 6, lane = t & 63;
    if (lane == 0) ws[wid] = d;
    __syncthreads();
    if (t == 0) bsum[b] = ws[0] + ws[1] + ws[2] + ws[3];
}

// ---------------------------------------------------------------------------
// k_scan2: per-block exclusive scan. Block offset = sum(bsum[0..b-1]) computed
// in-block; local wave-shuffle scan of 256 degs; write rowstart & cur.
// ---------------------------------------------------------------------------
__global__ __launch_bounds__(256) void k_scan2(const int* __restrict__ deg,
                                               const int* __restrict__ bsum,
                                               int* __restrict__ rowstart,
                                               int* __restrict__ cur) {
    int b = blockIdx.x, t = threadIdx.x;
    int node = b * 256 + t;
    int wid = t >> 6, lane = t & 63;

    // ---- block offset: sum of preceding block sums ----
    int partial = 0;
    for (int i = t; i < b; i += 256) partial += bsum[i];
    for (int o = 32; o > 0; o >>= 1) partial += __shfl_down(partial, o, 64);
    __shared__ int ws[4];
    __shared__ int sh_off;
    if (lane == 0) ws[wid] = partial;
    __syncthreads();
    if (t == 0) sh_off = ws[0] + ws[1] + ws[2] + ws[3];
    __syncthreads();
    int off = sh_off;

    // ---- local inclusive scan (wave shuffle + cross-wave LDS) ----
    int d = (node < N_NODES) ? deg[node] : 0;
    int incl = d;
    for (int o = 1; o < 64; o <<= 1) {
        int v = __shfl_up(incl, o, 64);
        if (lane >= o) incl += v;
    }
    __shared__ int wtot[4];
    if (lane == 63) wtot[wid] = incl;
    __syncthreads();
    int woff = 0;
    for (int w = 0; w < wid; ++w) woff += wtot[w];

    int excl = off + woff + incl - d;
    if (node < N_NODES) {
        rowstart[node] = excl;
        cur[node] = excl;
        if (node == N_NODES - 1) rowstart[N_NODES] = excl + d;
    }
}

// ---------------------------------------------------------------------------
// k_fill: scatter edges into CSR slots; record = {src, norm} packed as int2
// ---------------------------------------------------------------------------
__global__ void k_fill(const int* __restrict__ ei, const float* __restrict__ dinv,
                       int* __restrict__ cur, int2* __restrict__ edata) {
    int e = blockIdx.x * blockDim.x + threadIdx.x;
    if (e >= N_EDGES) return;
    int s = ei[e];
    int d = ei[N_EDGES + e];
    float nm = dinv[s] * dinv[d];
    int pos = atomicAdd(&cur[d], 1);
    edata[pos] = make_int2(s, __float_as_int(nm));
}

// ---------------------------------------------------------------------------
// k_gemm3: H[n,64] = X[n,K] @ W[K,64].
// 64 rows x 64 cols per block, 256 threads = 16 col-quads x 16 row-groups,
// thread tile = 4 rows x 4 cols. Only W staged in LDS (32KB max -> 5
// blocks/CU); X read directly from global: the 16 threads sharing a row quad
// are consecutive lanes of one wave -> same-address lanes merge into one
// transaction (16x reuse via coalescer, no LDS, no per-tile barrier).
// ---------------------------------------------------------------------------
__device__ __forceinline__ void fma4(float4& acc, const float4& xv,
                                     const float4& w0, const float4& w1,
                                     const float4& w2, const float4& w3) {
    acc.x += xv.x * w0.x + xv.y * w1.x + xv.z * w2.x + xv.w * w3.x;
    acc.y += xv.x * w0.y + xv.y * w1.y + xv.z * w2.y + xv.w * w3.y;
    acc.z += xv.x * w0.z + xv.y * w1.z + xv.z * w2.z + xv.w * w3.z;
    acc.w += xv.x * w0.w + xv.y * w1.w + xv.z * w2.w + xv.w * w3.w;
}

template <int K>
__global__ __launch_bounds__(256) void k_gemm3(const float* __restrict__ X,
                                               const float* __restrict__ W,
                                               float* __restrict__ H, int n) {
    constexpr int QK = K / 4;                 // float4 quads per row
    __shared__ float4 Ws[K * 16];             // [K][64] as quads
    const int tid = threadIdx.x;
    const int row0 = blockIdx.x * 64;

    for (int f = tid; f < K * 16; f += 256) Ws[f] = ((const float4*)W)[f];
    __syncthreads();

    const int c4 = tid & 15;                  // col quad
    const int r0 = row0 + ((tid >> 4) << 2);  // first of this thread's 4 rows
    const float4* Xq = (const float4*)X;

    float4 a0 = make_float4(0.f, 0.f, 0.f, 0.f);
    float4 a1 = a0, a2 = a0, a3 = a0;

    if (r0 + 3 < n) {                         // fast path (all but last block)
        const float4* xp0 = Xq + (size_t)r0 * QK;
        const float4* xp1 = xp0 + QK;
        const float4* xp2 = xp1 + QK;
        const float4* xp3 = xp2 + QK;
#pragma unroll 4
        for (int k4 = 0; k4 < QK; ++k4) {
            const float4 x0 = xp0[k4];
            const float4 x1 = xp1[k4];
            const float4 x2 = xp2[k4];
            const float4 x3 = xp3[k4];
            const float4 w0 = Ws[(k4 * 4 + 0) * 16 + c4];
            const float4 w1 = Ws[(k4 * 4 + 1) * 16 + c4];
            const float4 w2 = Ws[(k4 * 4 + 2) * 16 + c4];
            const float4 w3 = Ws[(k4 * 4 + 3) * 16 + c4];
            fma4(a0, x0, w0, w1, w2, w3);
            fma4(a1, x1, w0, w1, w2, w3);
            fma4(a2, x2, w0, w1, w2, w3);
            fma4(a3, x3, w0, w1, w2, w3);
        }
        ((float4*)H)[(size_t)(r0 + 0) * 16 + c4] = a0;
        ((float4*)H)[(size_t)(r0 + 1) * 16 + c4] = a1;
        ((float4*)H)[(size_t)(r0 + 2) * 16 + c4] = a2;
        ((float4*)H)[(size_t)(r0 + 3) * 16 + c4] = a3;
    } else {                                  // guarded tail (last block only)
        const float4 z = make_float4(0.f, 0.f, 0.f, 0.f);
        for (int k4 = 0; k4 < QK; ++k4) {
            const float4 x0 = (r0 + 0 < n) ? Xq[(size_t)(r0 + 0) * QK + k4] : z;
            const float4 x1 = (r0 + 1 < n) ? Xq[(size_t)(r0 + 1) * QK + k4] : z;
            const float4 x2 = (r0 + 2 < n) ? Xq[(size_t)(r0 + 2) * QK + k4] : z;
            const float4 x3 = (r0 + 3 < n) ? Xq[(size_t)(r0 + 3) * QK + k4] : z;
            const float4 w0 = Ws[(k4 * 4 + 0) * 16 + c4];
            const float4 w1 = Ws[(k4 * 4 + 1) * 16 + c4];
            const float4 w2 = Ws[(k4 * 4 + 2) * 16 + c4];
            const float4 w3 = Ws[(k4 * 4 + 3) * 16 + c4];
            fma4(a0, x0, w0, w1, w2, w3);
            fma4(a1, x1, w0, w1, w2, w3);
            fma4(a2, x2, w0, w1, w2, w3);
            fma4(a3, x3, w0, w1, w2, w3);
        }
        if (r0 + 0 < n) ((float4*)H)[(size_t)(r0 + 0) * 16 + c4] = a0;
        if (r0 + 1 < n) ((float4*)H)[(size_t)(r0 + 1) * 16 + c4] = a1;
        if (r0 + 2 < n) ((float4*)H)[(size_t)(r0 + 2) * 16 + c4] = a2;
        if (r0 + 3 < n) ((float4*)H)[(size_t)(r0 + 3) * 16 + c4] = a3;
    }
}

// ---------------------------------------------------------------------------
// k_gather: per-node CSR aggregation, fused bias + self-loop (+ ReLU).
// ---------------------------------------------------------------------------
template <bool RELU>
__global__ __launch_bounds__(256) void k_gather(const int* __restrict__ rowstart,
                                                const int2* __restrict__ edata,
                                                const float* __restrict__ h,
                                                const float* __restrict__ dinv,
                                                const float* __restrict__ bias,
                                                float* __restrict__ out) {
    int node = blockIdx.x * 16 + (threadIdx.x >> 4);
    int lane = threadIdx.x & 15;
    if (node >= N_NODES) return;

    int start = rowstart[node];
    int end   = rowstart[node + 1];

    float4 acc = make_float4(0.f, 0.f, 0.f, 0.f);
    for (int j = start; j < end; ++j) {
        int2 ed = edata[j];                       // broadcast across 16 lanes
        float nm = __int_as_float(ed.y);
        const float4 v = *reinterpret_cast<const float4*>(&h[(size_t)ed.x * 64 + lane * 4]);
        acc.x += v.x * nm;
        acc.y += v.y * nm;
        acc.z += v.z * nm;
        acc.w += v.w * nm;
    }
    // self loop + bias
    float di = dinv[node];
    float w = di * di;
    const float4 hv = *reinterpret_cast<const float4*>(&h[(size_t)node * 64 + lane * 4]);
    const float4 bv = *reinterpret_cast<const float4*>(&bias[lane * 4]);
    acc.x += hv.x * w + bv.x;
    acc.y += hv.y * w + bv.y;
    acc.z += hv.z * w + bv.z;
    acc.w += hv.w * w + bv.w;
    if (RELU) {
        acc.x = fmaxf(acc.x, 0.f);
        acc.y = fmaxf(acc.y, 0.f);
        acc.z = fmaxf(acc.z, 0.f);
        acc.w = fmaxf(acc.w, 0.f);
    }
    *reinterpret_cast<float4*>(&out[(size_t)node * 64 + lane * 4]) = acc;
}

extern "C" void kernel_launch(void* const* d_in, const int* in_sizes, int n_in,
                              void* d_out, int out_size, void* d_ws, size_t ws_size,
                              hipStream_t stream) {
    const float* x  = (const float*)d_in[0];
    const int*   ei = (const int*)d_in[1];    // [2, N_EDGES] int32
    const float* W1 = (const float*)d_in[2];
    const float* b1 = (const float*)d_in[3];
    const float* W2 = (const float*)d_in[4];
    const float* b2 = (const float*)d_in[5];
    float* out = (float*)d_out;

    // Workspace carve-up:
    //   deg[N] | rowstart[N+1] | cur[N] | dinv[N] | bsum[196] | edata[E]*8B |
    //   h[N*64] | a1[N*64]   ~= 33 MB
    int*   deg      = (int*)d_ws;
    int*   rowstart = deg + N_NODES;
    int*   cur      = rowstart + (N_NODES + 1);
    float* dinv     = (float*)(cur + N_NODES);
    int*   bsum     = (int*)(dinv + N_NODES);
    int2*  edata    = (int2*)(bsum + ((SCAN_BLOCKS + 1) & ~1));
    float* h        = (float*)(edata + N_EDGES);
    float* a1       = h + (size_t)N_NODES * 64;

    // --- CSR build ---
    k_zero<<<(N_NODES + 255) / 256, 256, 0, stream>>>(deg, N_NODES);
    k_hist<<<(N_EDGES + 255) / 256, 256, 0, stream>>>(ei, deg);
    k_dinv<<<(N_NODES + 255) / 256, 256, 0, stream>>>(deg, dinv, N_NODES);
    k_bsum<<<SCAN_BLOCKS, 256, 0, stream>>>(deg, bsum);
    k_scan2<<<SCAN_BLOCKS, 256, 0, stream>>>(deg, bsum, rowstart, cur);
    k_fill<<<(N_EDGES + 255) / 256, 256, 0, stream>>>(ei, dinv, cur, edata);

    // --- layer 1 ---
    k_gemm3<IN_DIM><<<(N_NODES + 63) / 64, 256, 0, stream>>>(x, W1, h, N_NODES);
    k_gather<true><<<(N_NODES + 15) / 16, 256, 0, stream>>>(rowstart, edata, h, dinv, b1, a1);

    // --- layer 2 ---
    k_gemm3<HID_DIM><<<(N_NODES + 63) / 64, 256, 0, stream>>>(a1, W2, h, N_NODES);
    k_gather<false><<<(N_NODES + 15) / 16, 256, 0, stream>>>(rowstart, edata, h, dinv, b2, out);
}